// Round 2
// baseline (324.276 us; speedup 1.0000x reference)
//
#include <hip/hip_runtime.h>
#include <hip/hip_bf16.h>
#include <stdint.h>

typedef unsigned short u16;

#define NINF (-__builtin_huge_valf())

__device__ __forceinline__ float bf2f(u16 h) {
    return __uint_as_float(((unsigned int)h) << 16);
}
__device__ __forceinline__ u16 f2bf(float f) {
    unsigned int u = __float_as_uint(f);
    u += 0x7FFFu + ((u >> 16) & 1u);   // round-to-nearest-even
    return (u16)(u >> 16);
}
__device__ __forceinline__ void unpack8(uint4 u, float* f) {
    f[0] = __uint_as_float(u.x << 16);
    f[1] = __uint_as_float(u.x & 0xFFFF0000u);
    f[2] = __uint_as_float(u.y << 16);
    f[3] = __uint_as_float(u.y & 0xFFFF0000u);
    f[4] = __uint_as_float(u.z << 16);
    f[5] = __uint_as_float(u.z & 0xFFFF0000u);
    f[6] = __uint_as_float(u.w << 16);
    f[7] = __uint_as_float(u.w & 0xFFFF0000u);
}
__device__ __forceinline__ void unpack4(uint2 u, float* f) {
    f[0] = __uint_as_float(u.x << 16);
    f[1] = __uint_as_float(u.x & 0xFFFF0000u);
    f[2] = __uint_as_float(u.y << 16);
    f[3] = __uint_as_float(u.y & 0xFFFF0000u);
}

// ---------------------------------------------------------------------------
// Prologue (fused): blocks [0,256)   -> proj_inv = v_inv @ W_in^T + b_in (bf16)
//                   blocks [256,640) -> proj_equi = v_equi @ W_coord^T  (bf16)
// ---------------------------------------------------------------------------
__global__ __launch_bounds__(256) void k_prologue(
    const float* __restrict__ v_inv,    // [2048, 256]
    const float* __restrict__ W_in,     // [256, 256] (o,i)
    const float* __restrict__ b_in,     // [256]
    u16* __restrict__ proj_inv,         // [2048, 256] bf16
    const float* __restrict__ v_equi,   // [6144, 64] (rows = b*n*3)
    const float* __restrict__ W_coord,  // [64, 64] (o,c)
    u16* __restrict__ proj_equi)        // [6144, 64] bf16
{
    int t = threadIdx.x;
    __shared__ float Xs[8][256];
    __shared__ float Es[16][64];

    if (blockIdx.x < 256) {
        int r0 = blockIdx.x * 8;
#pragma unroll
        for (int i = 0; i < 8; ++i)
            Xs[i][t] = v_inv[(size_t)(r0 + i) * 256 + t];
        __syncthreads();
        float acc[8];
        float bv = b_in[t];
#pragma unroll
        for (int r = 0; r < 8; ++r) acc[r] = bv;
        const float* wrow = W_in + t * 256;
        for (int i = 0; i < 256; i += 4) {
            float4 w = *(const float4*)(wrow + i);
#pragma unroll
            for (int r = 0; r < 8; ++r) {
                acc[r] += Xs[r][i + 0] * w.x;
                acc[r] += Xs[r][i + 1] * w.y;
                acc[r] += Xs[r][i + 2] * w.z;
                acc[r] += Xs[r][i + 3] * w.w;
            }
        }
#pragma unroll
        for (int r = 0; r < 8; ++r)
            proj_inv[(size_t)(r0 + r) * 256 + t] = f2bf(acc[r]);
    } else {
        int bi = blockIdx.x - 256;            // [0,384), 16 rows each
        const float* src = v_equi + (size_t)bi * 1024;
        ((float4*)Es)[t] = *(const float4*)(src + t * 4);
        __syncthreads();
        int o = t & 63, rr = t >> 6;
        float acc[4] = {0.f, 0.f, 0.f, 0.f};
        const float* wrow = W_coord + o * 64;
#pragma unroll
        for (int c = 0; c < 64; c += 4) {
            float4 w = *(const float4*)(wrow + c);
#pragma unroll
            for (int m = 0; m < 4; ++m) {
                int r = rr + 4 * m;
                acc[m] += Es[r][c + 0] * w.x + Es[r][c + 1] * w.y
                        + Es[r][c + 2] * w.z + Es[r][c + 3] * w.w;
            }
        }
        u16* dst = proj_equi + (size_t)bi * 1024;
#pragma unroll
        for (int m = 0; m < 4; ++m)
            dst[(rr + 4 * m) * 64 + o] = f2bf(acc[m]);
    }
}

// ---------------------------------------------------------------------------
// Fused attention kernel.
//   blocks [0,2048)    : equi attention, one (b,q) per block (body unchanged)
//   blocks [2048,4096) : inv attention, ONE (b,q) per block + fused W_out GEMV
// LDS is a union: equi path 27.3 KB dominates; inv path fits in 22.7 KB.
// ---------------------------------------------------------------------------
struct SmemEqui {
    float maskv[256];
    int   anyflag;
    int   pad[3];
    float part[32][195];
    float red_s[64];
    float red_s2[64];
    float out_s[3][64];
};
struct SmemInv {
    float maskv[256];
    int   anyflag;
    int   pad[3];
    float p_s[256][16];
    float sh_sp[4][16];
    float sh_s2p[4][16];
    float sh_s[16];
    float sh_s2[16];
    float red[4][256];
    float outi[256];
};
union SmemU {
    SmemEqui e;
    SmemInv  i;
};

__global__ __launch_bounds__(256) void k_fused_attn(
    const float* __restrict__ equi_msg,  // [B,256,256,64] fp32
    const float* __restrict__ inv_msg,   // [B,256,256,16] fp32
    const int* __restrict__ adj,         // [B,256,256]
    const u16* __restrict__ proj_equi,   // [B,256,3,64] bf16 (ws)
    const u16* __restrict__ proj_inv,    // [B,256,256] bf16 (ws)
    const float* __restrict__ W_eo,      // [64,64] (o,c)
    const float* __restrict__ b_eo,      // [64]
    const float* __restrict__ W_out,     // [256,256] (o,i)
    const float* __restrict__ b_out,     // [256]
    float* __restrict__ out)             // equi: [B,256,3,64] then inv: [B,256,256]
{
    __shared__ SmemU S;
    int t = threadIdx.x;

    if (blockIdx.x < 2048) {
        // ================= equi path (unchanged logic) =================
        int bq = blockIdx.x;
        int b = bq >> 8;

        if (t == 0) S.e.anyflag = 0;
        __syncthreads();
        int a = adj[(size_t)bq * 256 + t];
        if (a != 0) S.e.anyflag = 1;
        __syncthreads();
        S.e.maskv[t] = (a == 0 && S.e.anyflag != 0) ? NINF : 0.0f;
        __syncthreads();

        int kk = t >> 3;
        int c0 = (t & 7) * 8;
        float s[8], s2[8], a0[8], a1[8], a2[8];
#pragma unroll
        for (int u = 0; u < 8; ++u) { s[u] = 0.f; s2[u] = 0.f; a0[u] = 0.f; a1[u] = 0.f; a2[u] = 0.f; }

        const float* msg_base = equi_msg + (size_t)bq * 256 * 64;
        const u16* proj_base = proj_equi + (size_t)b * 256 * 192;

#pragma unroll 4
        for (int j = 0; j < 8; ++j) {
            int k = kk + 32 * j;
            float m = S.e.maskv[k];
            float4 m0 = *(const float4*)(msg_base + k * 64 + c0);
            float4 m1 = *(const float4*)(msg_base + k * 64 + c0 + 4);
            const u16* pb = proj_base + k * 192 + c0;
            uint4 up0 = *(const uint4*)(pb);
            uint4 up1 = *(const uint4*)(pb + 64);
            uint4 up2 = *(const uint4*)(pb + 128);
            float mv[8], p0[8], p1[8], p2[8];
            mv[0] = m0.x; mv[1] = m0.y; mv[2] = m0.z; mv[3] = m0.w;
            mv[4] = m1.x; mv[5] = m1.y; mv[6] = m1.z; mv[7] = m1.w;
            unpack8(up0, p0); unpack8(up1, p1); unpack8(up2, p2);
#pragma unroll
            for (int u = 0; u < 8; ++u) {
                float e = __expf(mv[u] + m);
                s[u] += e;
                s2[u] += e * e;
                a0[u] += e * p0[u];
                a1[u] += e * p1[u];
                a2[u] += e * p2[u];
            }
        }

#pragma unroll
        for (int u = 0; u < 8; ++u) {
            S.e.part[kk][c0 + u] = s[u];
            S.e.part[kk][65 + c0 + u] = s2[u];
        }
        __syncthreads();
        if (t < 128) {
            int qq = t >> 6, c = t & 63;
            float sum = 0.f;
#pragma unroll
            for (int x = 0; x < 32; ++x) sum += S.e.part[x][qq * 65 + c];
            if (qq == 0) S.e.red_s[c] = sum; else S.e.red_s2[c] = sum;
        }
        __syncthreads();
#pragma unroll
        for (int u = 0; u < 8; ++u) {
            S.e.part[kk][c0 + u] = a0[u];
            S.e.part[kk][65 + c0 + u] = a1[u];
            S.e.part[kk][130 + c0 + u] = a2[u];
        }
        __syncthreads();
        if (t < 192) {
            int d = t >> 6, c = t & 63;
            float sum = 0.f;
#pragma unroll
            for (int x = 0; x < 32; ++x) sum += S.e.part[x][d * 65 + c];
            float sv = S.e.red_s[c];
            float scale = sqrtf(S.e.red_s2[c]) / (sv * sv);
            S.e.out_s[d][c] = sum * scale;
        }
        __syncthreads();
        if (t < 192) {
            int d = t >> 6, o = t & 63;
            float acc = b_eo[o];
            const float* wr = W_eo + o * 64;
#pragma unroll
            for (int c4 = 0; c4 < 64; c4 += 4) {
                float4 w = *(const float4*)(wr + c4);
                acc += S.e.out_s[d][c4 + 0] * w.x;
                acc += S.e.out_s[d][c4 + 1] * w.y;
                acc += S.e.out_s[d][c4 + 2] * w.z;
                acc += S.e.out_s[d][c4 + 3] * w.w;
            }
            out[(size_t)bq * 192 + t] = acc;
        }
    } else {
        // ================= inv path: one (b,q) per block =================
        int bq = blockIdx.x - 2048;
        int b = bq >> 8;

        if (t == 0) S.i.anyflag = 0;
        __syncthreads();
        int a = adj[(size_t)bq * 256 + t];
        if (a != 0) S.i.anyflag = 1;
        __syncthreads();
        S.i.maskv[t] = (a == 0 && S.i.anyflag != 0) ? NINF : 0.0f;
        __syncthreads();

        // ---- pass 1: exps (float4 over 4 heads) + s/s2 via shuffle butterfly
        {
            int hq = t & 3;            // head quad: h = hq*4 .. hq*4+3
            int kkg = t >> 2;          // [0,64)
            const float* mb = inv_msg + (size_t)bq * 4096;
            float ss[4] = {0.f, 0.f, 0.f, 0.f};
            float ss2[4] = {0.f, 0.f, 0.f, 0.f};
#pragma unroll
            for (int j = 0; j < 4; ++j) {
                int k = kkg + 64 * j;
                float4 v = *(const float4*)(mb + k * 16 + hq * 4);
                float mval = S.i.maskv[k];
                float e0 = __expf(v.x + mval);
                float e1 = __expf(v.y + mval);
                float e2 = __expf(v.z + mval);
                float e3 = __expf(v.w + mval);
                *(float4*)(&S.i.p_s[k][hq * 4]) = make_float4(e0, e1, e2, e3);
                ss[0] += e0; ss[1] += e1; ss[2] += e2; ss[3] += e3;
                ss2[0] += e0 * e0; ss2[1] += e1 * e1;
                ss2[2] += e2 * e2; ss2[3] += e3 * e3;
            }
            // lane = (kkg&15)*4 + hq; reduce over the 16 k-groups of this wave
#pragma unroll
            for (int m = 4; m <= 32; m <<= 1) {
#pragma unroll
                for (int i = 0; i < 4; ++i) {
                    ss[i]  += __shfl_xor(ss[i], m);
                    ss2[i] += __shfl_xor(ss2[i], m);
                }
            }
            if ((t & 63) < 4) {
                int w = t >> 6;
                *(float4*)(&S.i.sh_sp[w][hq * 4])  = make_float4(ss[0], ss[1], ss[2], ss[3]);
                *(float4*)(&S.i.sh_s2p[w][hq * 4]) = make_float4(ss2[0], ss2[1], ss2[2], ss2[3]);
            }
        }
        __syncthreads();
        if (t < 32) {
            int sel = t >> 4, h = t & 15;
            if (sel == 0)
                S.i.sh_s[h] = S.i.sh_sp[0][h] + S.i.sh_sp[1][h]
                            + S.i.sh_sp[2][h] + S.i.sh_sp[3][h];
            else
                S.i.sh_s2[h] = S.i.sh_s2p[0][h] + S.i.sh_s2p[1][h]
                             + S.i.sh_s2p[2][h] + S.i.sh_s2p[3][h];
        }
        __syncthreads();

        // ---- pass 2: out_i[h,e] = sum_k p[k,h] * proj[b,k,h*16+e]
        {
            int kk2 = t >> 6, h = (t >> 2) & 15, eg = t & 3;
            float acc[4] = {0.f, 0.f, 0.f, 0.f};
            const u16* pb = proj_inv + (size_t)b * 65536 + h * 16 + eg * 4;
#pragma unroll 8
            for (int j = 0; j < 64; ++j) {
                int k = kk2 + 4 * j;
                uint2 u = *(const uint2*)(pb + (size_t)k * 256);
                float w[4]; unpack4(u, w);
                float p = S.i.p_s[k][h];
#pragma unroll
                for (int ii = 0; ii < 4; ++ii) acc[ii] += p * w[ii];
            }
#pragma unroll
            for (int ii = 0; ii < 4; ++ii)
                S.i.red[kk2][h * 16 + eg * 4 + ii] = acc[ii];
        }
        __syncthreads();
        {
            int h = t >> 4;
            float sum = S.i.red[0][t] + S.i.red[1][t] + S.i.red[2][t] + S.i.red[3][t];
            float sv = S.i.sh_s[h];
            S.i.outi[t] = sum * sqrtf(S.i.sh_s2[h]) / (sv * sv);
        }
        __syncthreads();

        // ---- fused epilogue: inv_updates[bq,o] = b_out[o] + outi . W_out[o,:]
        {
            float acc = b_out[t];
            const float* wrow = W_out + t * 256;
#pragma unroll 8
            for (int i = 0; i < 256; i += 4) {
                float4 w = *(const float4*)(wrow + i);
                acc += S.i.outi[i + 0] * w.x;
                acc += S.i.outi[i + 1] * w.y;
                acc += S.i.outi[i + 2] * w.z;
                acc += S.i.outi[i + 3] * w.w;
            }
            out[393216 + (size_t)bq * 256 + t] = acc;
        }
    }
}

// ---------------------------------------------------------------------------
extern "C" void kernel_launch(void* const* d_in, const int* in_sizes, int n_in,
                              void* d_out, int out_size, void* d_ws, size_t ws_size,
                              hipStream_t stream) {
    (void)in_sizes; (void)n_in; (void)out_size; (void)ws_size;

    const float* v_equi   = (const float*)d_in[0];
    const float* v_inv    = (const float*)d_in[1];
    const float* equi_msg = (const float*)d_in[2];
    const float* inv_msg  = (const float*)d_in[3];
    const int*   adj      = (const int*)d_in[4];
    const float* W_coord  = (const float*)d_in[5];
    const float* W_eo     = (const float*)d_in[6];
    const float* b_eo     = (const float*)d_in[7];
    const float* W_in     = (const float*)d_in[8];
    const float* b_in     = (const float*)d_in[9];
    const float* W_out    = (const float*)d_in[10];
    const float* b_out    = (const float*)d_in[11];
    float* out = (float*)d_out;

    char* ws = (char*)d_ws;
    u16* proj_equi = (u16*)(ws);                 // 786432 B
    u16* proj_inv  = (u16*)(ws + 786432);        // 1048576 B

    k_prologue<<<dim3(640), dim3(256), 0, stream>>>(
        v_inv, W_in, b_in, proj_inv, v_equi, W_coord, proj_equi);
    k_fused_attn<<<dim3(4096), dim3(256), 0, stream>>>(
        equi_msg, inv_msg, adj, proj_equi, proj_inv,
        W_eo, b_eo, W_out, b_out, out);
}